// Round 2
// baseline (1476.019 us; speedup 1.0000x reference)
//
#include <hip/hip_runtime.h>

#define BB     64
#define CC     12
#define LL     2048
#define KERNSZ 9
#define KK     8     // kernels per group
#define GG     32    // groups per branch (_G)
#define NPER   6
#define NDIL   8
#define PAD    512   // max halo = 4*d, d<=128
#define MAIN   2048
#define BUFSZ  (PAD + MAIN + PAD)   // 3072 floats = 12 KB per wave
#define WPB    4                    // waves per block -> 48 KB LDS -> 3 blocks/CU

typedef float f2 __attribute__((ext_vector_type(2)));

__device__ __forceinline__ f2 vmax2(f2 a, f2 b) {
    f2 r; r.x = fmaxf(a.x, b.x); r.y = fmaxf(a.y, b.y); return r;
}
__device__ __forceinline__ f2 vmin2(f2 a, f2 b) {
    f2 r; r.x = fminf(a.x, b.x); r.y = fminf(a.y, b.y); return r;
}

__global__ __launch_bounds__(256, 3) void hydra_kernel(
    const float* __restrict__ X,    // [B, C, L]
    const float* __restrict__ W,    // [NDIL, 2, KK*GG, 1, KERNSZ]
    const int*   __restrict__ I,    // [NDIL, 2, GG, NPER]
    float*       __restrict__ out)  // [B, 8192]
{
    __shared__ float lds[WPB][BUFSZ];

    const int tid  = threadIdx.x;
    const int wave = tid >> 6;
    const int lane = tid & 63;
    const int wid  = blockIdx.x * WPB + wave;   // 0..32767
    // task decode: wid = b*512 + di*64 + dif*32 + g
    const int b   = wid >> 9;
    const int r   = wid & 511;
    const int di  = r >> 6;
    const int r2  = r & 63;
    const int dif = r2 >> 5;
    const int g   = r2 & 31;
    const int d   = 1 << di;
    const int Lp  = LL - dif;          // 2048 (X) or 2047 (diff X)

    float* buf = lds[wave];
    float* sel = buf + PAD;

    // ---- zero halo pads (branchless dilated taps later) ----
    #pragma unroll
    for (int i = 0; i < PAD; i += 128) {
        *(f2*)(buf + i + 2 * lane)              = f2{0.f, 0.f};
        *(f2*)(buf + PAD + MAIN + i + 2 * lane) = f2{0.f, 0.f};
    }

    // ---- phase 1: channel-subset sum (and diff) into sel[0..2047] ----
    const int* Ig = I + ((size_t)((di * 2 + dif) * GG + g)) * NPER;
    const float* xb = X + (size_t)b * CC * LL;
    const float* c0 = xb + Ig[0] * LL;
    const float* c1 = xb + Ig[1] * LL;
    const float* c2 = xb + Ig[2] * LL;
    const float* c3 = xb + Ig[3] * LL;
    const float* c4 = xb + Ig[4] * LL;
    const float* c5 = xb + Ig[5] * LL;

    if (!dif) {
        #pragma unroll 1
        for (int q = 0; q < 16; ++q) {
            int pp = (q * 64 + lane) * 2;
            f2 s = *(const f2*)(c0 + pp) + *(const f2*)(c1 + pp)
                 + *(const f2*)(c2 + pp) + *(const f2*)(c3 + pp)
                 + *(const f2*)(c4 + pp) + *(const f2*)(c5 + pp);
            *(f2*)(sel + pp) = s;
        }
    } else {
        // diff(sum of channels) == sum of diff(channels); compute directly
        // from global to avoid any in-place LDS RAW hazard.
        #pragma unroll 1
        for (int q = 0; q < 16; ++q) {
            int pp = (q * 64 + lane) * 2;
            int pn = pp + 2; if (pn > LL - 1) pn = LL - 1;  // clamp (value unused there)
            f2 sc = *(const f2*)(c0 + pp) + *(const f2*)(c1 + pp)
                  + *(const f2*)(c2 + pp) + *(const f2*)(c3 + pp)
                  + *(const f2*)(c4 + pp) + *(const f2*)(c5 + pp);
            float sn = c0[pn] + c1[pn] + c2[pn] + c3[pn] + c4[pn] + c5[pn];
            f2 v;
            v.x = sc.y - sc.x;
            v.y = sn - sc.y;
            if (pp + 1 == LL - 1) v.y = 0.0f;   // sel[2047] acts as zero pad
            *(f2*)(sel + pp) = v;
        }
    }

    // ---- phase 2: dilated conv + max/min equality-masked accumulation ----
    // W pointer is wave-uniform -> weights live in SGPRs.
    const float* Wg = W + (size_t)((di * 2 + dif) * (KK * GG) + g * KK) * KERNSZ;
    float w[KK][KERNSZ];
    #pragma unroll
    for (int k = 0; k < KK; ++k)
        #pragma unroll
        for (int j = 0; j < KERNSZ; ++j)
            w[k][j] = Wg[k * KERNSZ + j];

    const float NANF = __uint_as_float(0x7fc00000u);

    f2 accM[KK], accN[KK];
    #pragma unroll
    for (int k = 0; k < KK; ++k) { accM[k] = f2{0.f, 0.f}; accN[k] = f2{0.f, 0.f}; }

    #pragma unroll 1
    for (int q = 0; q < 16; ++q) {
        int pp = (q * 64 + lane) * 2;   // even position; lane handles pp, pp+1

        f2 v[KK];
        #pragma unroll
        for (int j = 0; j < KERNSZ; ++j) {
            int o = pp + (j - 4) * d;
            f2 s; s.x = sel[o]; s.y = sel[o + 1];   // -> ds_read2_b32
            if (j == 0) {
                #pragma unroll
                for (int k = 0; k < KK; ++k) v[k] = w[k][0] * s;
            } else {
                #pragma unroll
                for (int k = 0; k < KK; ++k) v[k] = v[k] + w[k][j] * s;  // v_pk_fma
            }
        }

        f2 mv = vmax2(vmax2(vmax2(v[0], v[1]), vmax2(v[2], v[3])),
                      vmax2(vmax2(v[4], v[5]), vmax2(v[6], v[7])));
        f2 nv = vmin2(vmin2(vmin2(v[0], v[1]), vmin2(v[2], v[3])),
                      vmin2(vmin2(v[4], v[5]), vmin2(v[6], v[7])));

        // exclude nonexistent position 2047 on diff branch: NaN never equals
        if (pp + 1 >= Lp) { mv.y = NANF; nv.y = NANF; }

        #pragma unroll
        for (int k = 0; k < KK; ++k) {
            f2 a;
            a.x = (v[k].x == mv.x) ? v[k].x : 0.0f;
            a.y = (v[k].y == mv.y) ? v[k].y : 0.0f;
            accM[k] += a;                            // v_pk_add
            f2 c;
            c.x = (v[k].x == nv.x) ? 1.0f : 0.0f;
            c.y = (v[k].y == nv.y) ? 1.0f : 0.0f;
            accN[k] += c;
        }
    }

    // ---- wave butterfly reduction of the 16 accumulators ----
    float* o = out + (size_t)b * 8192 + (size_t)((di * 2 + dif) * 2) * 256 + g * KK;
    #pragma unroll
    for (int k = 0; k < KK; ++k) {
        float a = accM[k].x + accM[k].y;
        float c = accN[k].x + accN[k].y;
        #pragma unroll
        for (int off = 32; off > 0; off >>= 1) {
            a += __shfl_xor(a, off, 64);
            c += __shfl_xor(c, off, 64);
        }
        if (lane == 0) {
            o[k]       = a;   // count_max block (which=0)
            o[256 + k] = c;   // count_min block (which=1)
        }
    }
}

extern "C" void kernel_launch(void* const* d_in, const int* in_sizes, int n_in,
                              void* d_out, int out_size, void* d_ws, size_t ws_size,
                              hipStream_t stream) {
    const float* X = (const float*)d_in[0];
    const float* W = (const float*)d_in[1];
    const int*   I = (const int*)d_in[2];
    float* out = (float*)d_out;

    const int total_waves = BB * NDIL * 2 * GG;       // 32768
    const int blocks = total_waves / WPB;             // 8192
    hydra_kernel<<<blocks, 256, 0, stream>>>(X, W, I, out);
}

// Round 3
// 269.943 us; speedup vs baseline: 5.4679x; 5.4679x over previous
//
#include <hip/hip_runtime.h>

#define BB     64
#define CC     12
#define LL     2048
#define KERNSZ 9
#define KK     8     // kernels per group
#define GG     32    // groups per branch (_G)
#define NPER   6
#define NDIL   8
#define PAD    512   // max halo = 4*d, d<=128
#define MAIN   2048
#define BUFSZ  (PAD + MAIN + PAD)   // 3072 floats = 12 KB per wave
#define WPB    4                    // waves per block -> 48 KB LDS -> 3 blocks/CU

// Phase 2, specialized on compile-time dilation D so the 9 tap offsets are
// immediates (ds_read2_b32 pairing, no per-tap address adds). di is
// block-uniform (16 consecutive blocks share di) so the dispatch switch is a
// uniform scalar branch.
template <int D>
__device__ __forceinline__ void run_phase2(
    const float* __restrict__ sel, int lane, int dif,
    const float (&w)[KK][KERNSZ], float (&accM)[KK], float (&accN)[KK])
{
    const float NANF = __uint_as_float(0x7fc00000u);

    for (int q = 0; q < 32; ++q) {
        const int pos = q * 64 + lane;
        const float* p = sel + pos - 4 * D;   // left-most tap; pads make all 9 valid

        float s[KERNSZ];
        #pragma unroll
        for (int j = 0; j < KERNSZ; ++j)
            s[j] = p[j * D];                  // compile-time imm offsets

        float v[KK];
        #pragma unroll
        for (int k = 0; k < KK; ++k) {
            float acc = w[k][0] * s[0];
            #pragma unroll
            for (int j = 1; j < KERNSZ; ++j)
                acc = fmaf(w[k][j], s[j], acc);
            v[k] = acc;
        }

        // balanced max/min trees (compiler folds to v_max3/v_min3)
        float ma = fmaxf(fmaxf(v[0], v[1]), fmaxf(v[2], v[3]));
        float mb = fmaxf(fmaxf(v[4], v[5]), fmaxf(v[6], v[7]));
        float mv = fmaxf(ma, mb);
        float na = fminf(fminf(v[0], v[1]), fminf(v[2], v[3]));
        float nb = fminf(fminf(v[4], v[5]), fminf(v[6], v[7]));
        float nv = fminf(na, nb);

        // only invalid output position: pos==2047 on diff branch.
        // NaN never compares equal -> contributes nothing below.
        if (dif && q == 31) {
            if (lane == 63) { mv = NANF; nv = NANF; }
        }

        #pragma unroll
        for (int k = 0; k < KK; ++k) {
            accM[k] += (v[k] == mv) ? v[k] : 0.0f;   // exact: mv bit-equals winner
            accN[k] += (v[k] == nv) ? 1.0f : 0.0f;
        }
    }
}

__global__ __launch_bounds__(256) void hydra_kernel(
    const float* __restrict__ X,    // [B, C, L]
    const float* __restrict__ W,    // [NDIL, 2, KK*GG, 1, KERNSZ]
    const int*   __restrict__ I,    // [NDIL, 2, GG, NPER]
    float*       __restrict__ out)  // [B, 8192]
{
    __shared__ float lds[WPB][BUFSZ];

    const int tid  = threadIdx.x;
    const int wave = tid >> 6;
    const int lane = tid & 63;
    const int wid  = blockIdx.x * WPB + wave;   // 0..32767
    // task decode: wid = b*512 + di*64 + dif*32 + g
    const int b   = wid >> 9;
    const int r   = wid & 511;
    const int di  = r >> 6;
    const int r2  = r & 63;
    const int dif = r2 >> 5;
    const int g   = r2 & 31;

    float* buf = lds[wave];
    float* sel = buf + PAD;

    // ---- zero halo pads ----
    #pragma unroll
    for (int i = 0; i < PAD; i += 64) {
        buf[i + lane]              = 0.0f;
        buf[PAD + MAIN + i + lane] = 0.0f;
    }

    // ---- phase 1: channel-subset sum S into sel[0..2047] ----
    const int* Ig = I + ((size_t)((di * 2 + dif) * GG + g)) * NPER;
    const float* xb = X + (size_t)b * CC * LL;
    const float* p0 = xb + Ig[0] * LL;
    const float* p1 = xb + Ig[1] * LL;
    const float* p2 = xb + Ig[2] * LL;
    const float* p3 = xb + Ig[3] * LL;
    const float* p4 = xb + Ig[4] * LL;
    const float* p5 = xb + Ig[5] * LL;

    for (int q = 0; q < 32; ++q) {
        int pos = q * 64 + lane;
        float s = p0[pos] + p1[pos] + p2[pos] + p3[pos] + p4[pos] + p5[pos];
        sel[pos] = s;
    }

    if (dif) {
        // in-place wave-synchronous diff (validated in R1): per iteration the
        // ds_reads (pos, pos+1) issue before the ds_write; lane63's pos+1 read
        // targets data only rewritten at iteration q+1. sel[2048] is zero pad.
        for (int q = 0; q < 32; ++q) {
            int pos = q * 64 + lane;
            float a  = sel[pos];
            float an = sel[pos + 1];
            float v  = (pos == (LL - 1)) ? 0.0f : (an - a);
            sel[pos] = v;   // sel[2047] := 0 so neighboring taps see zero pad
        }
    }

    // ---- weights: wave-uniform pointer -> scalar (SGPR) loads ----
    const float* Wg = W + (size_t)((di * 2 + dif) * (KK * GG) + g * KK) * KERNSZ;
    float w[KK][KERNSZ];
    #pragma unroll
    for (int k = 0; k < KK; ++k)
        #pragma unroll
        for (int j = 0; j < KERNSZ; ++j)
            w[k][j] = Wg[k * KERNSZ + j];

    float accM[KK], accN[KK];
    #pragma unroll
    for (int k = 0; k < KK; ++k) { accM[k] = 0.0f; accN[k] = 0.0f; }

    switch (di) {   // block-uniform branch
        case 0: run_phase2<1>  (sel, lane, dif, w, accM, accN); break;
        case 1: run_phase2<2>  (sel, lane, dif, w, accM, accN); break;
        case 2: run_phase2<4>  (sel, lane, dif, w, accM, accN); break;
        case 3: run_phase2<8>  (sel, lane, dif, w, accM, accN); break;
        case 4: run_phase2<16> (sel, lane, dif, w, accM, accN); break;
        case 5: run_phase2<32> (sel, lane, dif, w, accM, accN); break;
        case 6: run_phase2<64> (sel, lane, dif, w, accM, accN); break;
        default: run_phase2<128>(sel, lane, dif, w, accM, accN); break;
    }

    // ---- wave butterfly reduction of the 16 accumulators ----
    float* o = out + (size_t)b * 8192 + (size_t)((di * 2 + dif) * 2) * 256 + g * KK;
    #pragma unroll
    for (int k = 0; k < KK; ++k) {
        float a = accM[k];
        float c = accN[k];
        #pragma unroll
        for (int off = 32; off > 0; off >>= 1) {
            a += __shfl_xor(a, off, 64);
            c += __shfl_xor(c, off, 64);
        }
        if (lane == 0) {
            o[k]       = a;   // count_max block (which=0)
            o[256 + k] = c;   // count_min block (which=1)
        }
    }
}

extern "C" void kernel_launch(void* const* d_in, const int* in_sizes, int n_in,
                              void* d_out, int out_size, void* d_ws, size_t ws_size,
                              hipStream_t stream) {
    const float* X = (const float*)d_in[0];
    const float* W = (const float*)d_in[1];
    const int*   I = (const int*)d_in[2];
    float* out = (float*)d_out;

    const int total_waves = BB * NDIL * 2 * GG;       // 32768
    const int blocks = total_waves / WPB;             // 8192
    hydra_kernel<<<blocks, 256, 0, stream>>>(X, W, I, out);
}

// Round 4
// 269.831 us; speedup vs baseline: 5.4702x; 1.0004x over previous
//
#include <hip/hip_runtime.h>
#include <stdint.h>

#define BB     64
#define CC     12
#define LL     2048
#define KERNSZ 9
#define KK     8     // kernels per group
#define GG     32    // groups per branch (_G)
#define NPER   6
#define NDIL   8
#define PAD    512   // max halo = 4*d, d<=128
#define MAIN   2048
#define BUFSZ  (PAD + MAIN + PAD)   // 3072 floats = 12 KB per wave
#define WPB    4                    // waves per block -> 48 KB LDS -> 3 blocks/CU

typedef float f2 __attribute__((ext_vector_type(2)));

// acc.{lo,hi} += t.lo * w.{lo,hi}   (tap broadcast via op_sel_hi[0]=0;
// weights are a wave-uniform SGPR pair -> no VGPR replication, no spill)
__device__ __forceinline__ void pk_fma_bcast(f2& acc, const f2& t, uint64_t wpair) {
    asm("v_pk_fma_f32 %0, %1, %2, %0 op_sel:[0,0,0] op_sel_hi:[0,1,1]"
        : "+v"(acc) : "v"(t), "s"(wpair));
}
__device__ __forceinline__ f2 pk_mul_bcast(const f2& t, uint64_t wpair) {
    f2 d;
    asm("v_pk_mul_f32 %0, %1, %2 op_sel:[0,0] op_sel_hi:[0,1]"
        : "=v"(d) : "v"(t), "s"(wpair));
    return d;
}

// Phase 2, specialized on compile-time dilation D (tap offsets are immediates).
template <int D>
__device__ __forceinline__ void run_phase2(
    const float* __restrict__ sel, int lane, int dif,
    const uint64_t (&wp)[4][KERNSZ], float (&accM)[KK], uint32_t (&accN)[KK])
{
    const float NANF = __uint_as_float(0x7fc00000u);

    for (int q = 0; q < 32; ++q) {
        const int pos = q * 64 + lane;
        const float* p = sel + pos - 4 * D;   // pads make all 9 taps valid

        f2 t[KERNSZ];                          // only .x meaningful; f2 forces
        #pragma unroll                         // even-aligned VGPR pair for asm
        for (int j = 0; j < KERNSZ; ++j)
            t[j].x = p[j * D];

        f2 v2[4];                              // (v0,v1)(v2,v3)(v4,v5)(v6,v7)
        #pragma unroll
        for (int c = 0; c < 4; ++c)
            v2[c] = pk_mul_bcast(t[0], wp[c][0]);
        #pragma unroll
        for (int j = 1; j < KERNSZ; ++j)
            #pragma unroll
            for (int c = 0; c < 4; ++c)
                pk_fma_bcast(v2[c], t[j], wp[c][j]);

        float v[KK] = { v2[0].x, v2[0].y, v2[1].x, v2[1].y,
                        v2[2].x, v2[2].y, v2[3].x, v2[3].y };

        float ma = fmaxf(fmaxf(v[0], v[1]), fmaxf(v[2], v[3]));
        float mb = fmaxf(fmaxf(v[4], v[5]), fmaxf(v[6], v[7]));
        float mv = fmaxf(ma, mb);
        float na = fminf(fminf(v[0], v[1]), fminf(v[2], v[3]));
        float nb = fminf(fminf(v[4], v[5]), fminf(v[6], v[7]));
        float nv = fminf(na, nb);

        // only invalid output position: pos==2047 on diff branch.
        // NaN never compares equal -> contributes nothing below.
        if (dif && q == 31) {
            if (lane == 63) { mv = NANF; nv = NANF; }
        }

        #pragma unroll
        for (int k = 0; k < KK; ++k) {
            accM[k] += (v[k] == mv) ? v[k] : 0.0f;   // exact: mv bit-equals winner
            accN[k] += (v[k] == nv) ? 1u : 0u;       // v_cmp + v_addc
        }
    }
}

__global__ __launch_bounds__(256) void hydra_kernel(
    const float* __restrict__ X,    // [B, C, L]
    const float* __restrict__ W,    // [NDIL, 2, KK*GG, 1, KERNSZ]
    const int*   __restrict__ I,    // [NDIL, 2, GG, NPER]
    float*       __restrict__ out)  // [B, 8192]
{
    __shared__ float lds[WPB][BUFSZ];

    const int tid  = threadIdx.x;
    const int wave = tid >> 6;
    const int lane = tid & 63;
    const int wid  = blockIdx.x * WPB + wave;   // 0..32767
    // task decode: wid = b*512 + di*64 + dif*32 + g
    const int b   = wid >> 9;
    const int r   = wid & 511;
    const int di  = r >> 6;
    const int r2  = r & 63;
    const int dif = r2 >> 5;
    const int g   = r2 & 31;

    float* buf = lds[wave];
    float* sel = buf + PAD;

    // ---- zero halo pads ----
    #pragma unroll
    for (int i = 0; i < PAD; i += 64) {
        buf[i + lane]              = 0.0f;
        buf[PAD + MAIN + i + lane] = 0.0f;
    }

    // ---- phase 1: channel-subset sum S into sel[0..2047] ----
    const int* Ig = I + ((size_t)((di * 2 + dif) * GG + g)) * NPER;
    const float* xb = X + (size_t)b * CC * LL;
    const float* p0 = xb + Ig[0] * LL;
    const float* p1 = xb + Ig[1] * LL;
    const float* p2 = xb + Ig[2] * LL;
    const float* p3 = xb + Ig[3] * LL;
    const float* p4 = xb + Ig[4] * LL;
    const float* p5 = xb + Ig[5] * LL;

    for (int q = 0; q < 32; ++q) {
        int pos = q * 64 + lane;
        float s = p0[pos] + p1[pos] + p2[pos] + p3[pos] + p4[pos] + p5[pos];
        sel[pos] = s;
    }

    if (dif) {
        // in-place wave-synchronous diff (validated R1/R3): reads of pos,pos+1
        // issue before the write; lane63's pos+1 read targets data rewritten
        // only at iteration q+1. sel[2048] is the zeroed right pad.
        for (int q = 0; q < 32; ++q) {
            int pos = q * 64 + lane;
            float a  = sel[pos];
            float an = sel[pos + 1];
            float v  = (pos == (LL - 1)) ? 0.0f : (an - a);
            sel[pos] = v;
        }
    }

    // ---- weights: wave-uniform scalar loads, packed into SGPR pairs ----
    const float* Wg = W + (size_t)((di * 2 + dif) * (KK * GG) + g * KK) * KERNSZ;
    uint64_t wp[4][KERNSZ];   // wp[c][j] = (w[2c][j], w[2c+1][j])
    #pragma unroll
    for (int c = 0; c < 4; ++c)
        #pragma unroll
        for (int j = 0; j < KERNSZ; ++j) {
            uint32_t lo = __float_as_uint(Wg[(2 * c)     * KERNSZ + j]);
            uint32_t hi = __float_as_uint(Wg[(2 * c + 1) * KERNSZ + j]);
            wp[c][j] = (uint64_t)lo | ((uint64_t)hi << 32);
        }

    float    accM[KK];
    uint32_t accN[KK];
    #pragma unroll
    for (int k = 0; k < KK; ++k) { accM[k] = 0.0f; accN[k] = 0u; }

    switch (di) {   // block-uniform branch
        case 0: run_phase2<1>  (sel, lane, dif, wp, accM, accN); break;
        case 1: run_phase2<2>  (sel, lane, dif, wp, accM, accN); break;
        case 2: run_phase2<4>  (sel, lane, dif, wp, accM, accN); break;
        case 3: run_phase2<8>  (sel, lane, dif, wp, accM, accN); break;
        case 4: run_phase2<16> (sel, lane, dif, wp, accM, accN); break;
        case 5: run_phase2<32> (sel, lane, dif, wp, accM, accN); break;
        case 6: run_phase2<64> (sel, lane, dif, wp, accM, accN); break;
        default: run_phase2<128>(sel, lane, dif, wp, accM, accN); break;
    }

    // ---- wave butterfly reduction of the 16 accumulators ----
    float* o = out + (size_t)b * 8192 + (size_t)((di * 2 + dif) * 2) * 256 + g * KK;
    #pragma unroll
    for (int k = 0; k < KK; ++k) {
        float a = accM[k];
        unsigned c = accN[k];
        #pragma unroll
        for (int off = 32; off > 0; off >>= 1) {
            a += __shfl_xor(a, off, 64);
            c += __shfl_xor(c, off, 64);
        }
        if (lane == 0) {
            o[k]       = a;          // count_max block (which=0)
            o[256 + k] = (float)c;   // count_min block (which=1)
        }
    }
}

extern "C" void kernel_launch(void* const* d_in, const int* in_sizes, int n_in,
                              void* d_out, int out_size, void* d_ws, size_t ws_size,
                              hipStream_t stream) {
    const float* X = (const float*)d_in[0];
    const float* W = (const float*)d_in[1];
    const int*   I = (const int*)d_in[2];
    float* out = (float*)d_out;

    const int total_waves = BB * NDIL * 2 * GG;       // 32768
    const int blocks = total_waves / WPB;             // 8192
    hydra_kernel<<<blocks, 256, 0, stream>>>(X, W, I, out);
}